// Round 10
// baseline (2970.009 us; speedup 1.0000x reference)
//
#include <hip/hip_runtime.h>
#include <hip/hip_bf16.h>

#define GV 1024
#define BATCH 128
#define M_TOT (BATCH * GV)   // 131072 rows
#define CHEB_K 5

typedef __bf16 bf16x8 __attribute__((ext_vector_type(8)));
typedef float  f32x4  __attribute__((ext_vector_type(4)));

// Wb offsets (bf16 elems). L0: [96][32] (f=k*3+c, pad to 32).
// L1..6: [Co][KdP], KdP=(Ci/16)*96; per 16-ch chunk cs: cols 96cs+16k+cl
// (k=0..4, cl=c%16), cols 96cs+80..95 zero-padded (K32-blocks: S0S1|S2S3|S4,0).
#define WOFF0 0
#define WOFF1 3072
#define WOFF2 58368
#define WOFF3 113664
#define WOFF4 224256
#define WOFF5 445440
#define WOFF6 666624
#define WTOT  777216

// 4-slot swizzle: float addr of (node ln, slot s) = SWA4(ln) ^ (s*4)
#define SWA4(ln) ((ln) * 16 + ((((ln) + ((ln) >> 3)) & 3) * 4))
#define LD4(B, A) (*(const f32x4*)((B) + (A)))
#define ST4(B, A, V) (*(f32x4*)((B) + (A)) = (V))
#define Z4 ((f32x4){0.f, 0.f, 0.f, 0.f})

// ---------------------------------------------------------------------------
__global__ void k_convw_all(const float* __restrict__ w0, const float* __restrict__ w1,
                            const float* __restrict__ w2, const float* __restrict__ w3,
                            const float* __restrict__ w4, const float* __restrict__ w5,
                            const float* __restrict__ w6, __hip_bfloat16* __restrict__ Wb) {
    const int li = blockIdx.y;
    const int CI[7]     = {3, 96, 96, 96, 192, 192, 192};
    const int SZ[7]     = {3072, 55296, 55296, 110592, 221184, 221184, 110592};
    const size_t OFF[7] = {WOFF0, WOFF1, WOFF2, WOFF3, WOFF4, WOFF5, WOFF6};
    const float* Ws[7]  = {w0, w1, w2, w3, w4, w5, w6};
    int idx = blockIdx.x * 256 + threadIdx.x;
    if (idx >= SZ[li]) return;
    const float* W = Ws[li];
    float v = 0.f;
    if (li == 0) {
        int f = idx & 31;
        if (f < 15) { int o = idx >> 5; int k = f / 3, c = f % 3; v = W[o * 15 + c * 5 + k]; }
    } else {
        int Ci = CI[li];
        int KdP = (Ci / 16) * 96;
        int o = idx / KdP, p = idx - o * KdP;
        int cs = p / 96, r = p - cs * 96;
        int k = r >> 4, cl = r & 15;
        if (k < 5) v = W[(size_t)o * 5 * Ci + (cs * 16 + cl) * 5 + k];
    }
    Wb[OFF[li] + idx] = __float2bfloat16(v);
}

// ---------------------------------------------------------------------------
__global__ __launch_bounds__(512, 4)
void k_cheb0(const float* __restrict__ X, __hip_bfloat16* __restrict__ F) {
    __shared__ float T[3][3072];
    int tid = threadIdx.x;
    int b = blockIdx.x;
    size_t fBase = ((size_t)b) << 10;
    for (int i = tid; i < 3072; i += 512) {
        int u = i / 3, c = i - (i / 3) * 3;
        float v = X[((size_t)b * 3 + c) * GV + u];
        F[(fBase + u) * 32 + c] = __float2bfloat16(v);
        int gi = u >> 5, gj = u & 31;
        int deg = (gi > 0) + (gi < 31) + (gj > 0) + (gj < 31);
        T[0][i] = v * rsqrtf((float)deg);
    }
    for (int i = tid; i < 1024 * 17; i += 512) {
        int u = i / 17, f = i - (i / 17) * 17;
        F[(fBase + u) * 32 + 15 + f] = __float2bfloat16(0.f);
    }
    __syncthreads();
    for (int k = 1; k < CHEB_K; ++k) {
        const float* src = T[(k - 1) % 3];
        const float* old = T[(k + 1) % 3];
        float* dst = T[k % 3];
        for (int i = tid; i < 3072; i += 512) {
            int u = i / 3, c = i - (i / 3) * 3;
            int gi = u >> 5, gj = u & 31;
            float s = 0.f;
            if (gi > 0)  s += src[i - 96];
            if (gi < 31) s += src[i + 96];
            if (gj > 0)  s += src[i - 3];
            if (gj < 31) s += src[i + 3];
            int deg = (gi > 0) + (gi < 31) + (gj > 0) + (gj < 31);
            float invdeg = (deg == 4) ? 0.25f : (deg == 3 ? (1.f / 3.f) : 0.5f);
            float val = (k == 1) ? (-s * invdeg) : (-2.f * invdeg * s - old[i]);
            dst[i] = val;
            F[(fBase + u) * 32 + k * 3 + c] = __float2bfloat16(val * sqrtf((float)deg));
        }
        __syncthreads();
    }
}

// ---------------------------------------------------------------------------
__global__ __launch_bounds__(256, 2)
void k_gemm_l0(const __hip_bfloat16* __restrict__ A, const __hip_bfloat16* __restrict__ Bw,
               float* __restrict__ Y, float* __restrict__ stats) {
    __shared__ float ls[192];
    int tid = threadIdx.x;
    for (int t = tid; t < 192; t += 256) ls[t] = 0.f;
    __syncthreads();
    int lane = tid & 63, wv = tid >> 6;
    int col = lane & 15, quad = lane >> 4;
    size_t m0 = (size_t)blockIdx.x * 128 + wv * 32;
    f32x4 acc[2][6];
    #pragma unroll
    for (int t = 0; t < 2; ++t)
        #pragma unroll
        for (int n = 0; n < 6; ++n) acc[t][n] = Z4;
    bf16x8 a0 = *(const bf16x8*)(A + (m0 + col) * 32 + quad * 8);
    bf16x8 a1 = *(const bf16x8*)(A + (m0 + 16 + col) * 32 + quad * 8);
    #pragma unroll
    for (int n = 0; n < 6; ++n) {
        bf16x8 bf = *(const bf16x8*)(Bw + (size_t)(n * 16 + col) * 32 + quad * 8);
        acc[0][n] = __builtin_amdgcn_mfma_f32_16x16x32_bf16(a0, bf, acc[0][n], 0, 0, 0);
        acc[1][n] = __builtin_amdgcn_mfma_f32_16x16x32_bf16(a1, bf, acc[1][n], 0, 0, 0);
    }
    int b = (int)(m0 >> 10);
    int v0 = (int)(m0 & 1023);
    #pragma unroll
    for (int t = 0; t < 2; ++t) {
        #pragma unroll
        for (int n = 0; n < 6; ++n) {
            int cg = n * 16 + col;
            int vv = v0 + t * 16 + quad * 4;
            f32x4 val = acc[t][n];
            *(f32x4*)(Y + ((size_t)b * 96 + cg) * 1024 + vv) = val;
            float s1 = val[0] + val[1] + val[2] + val[3];
            float s2 = val[0]*val[0] + val[1]*val[1] + val[2]*val[2] + val[3]*val[3];
            s1 += __shfl_xor(s1, 16, 64); s1 += __shfl_xor(s1, 32, 64);
            s2 += __shfl_xor(s2, 16, 64); s2 += __shfl_xor(s2, 32, 64);
            if (quad == 0) { atomicAdd(&ls[cg], s1); atomicAdd(&ls[96 + cg], s2); }
        }
    }
    __syncthreads();
    for (int t = tid; t < 192; t += 256) atomicAdd(&stats[t], ls[t]);
}

// ---------------------------------------------------------------------------
__device__ __forceinline__ bf16x8 pack8(f32x4 lo, f32x4 hi) {
    union { __hip_bfloat16 h[8]; bf16x8 v; } u;
    #pragma unroll
    for (int e = 0; e < 4; ++e) { u.h[e] = __float2bfloat16(lo[e]); u.h[4 + e] = __float2bfloat16(hi[e]); }
    return u.v;
}

// ---------------------------------------------------------------------------
// FUSED layer, 16-channel chunks -> 64KB LDS pair -> 2 blocks/CU (16 waves).
// K32 MFMA spans two degrees: per chunk the K-blocks are (S0|S1),(S2|S3),(S4|0);
// A-fragment buffer chosen by quad>>1; pre-read regs carry S_d across the phase
// that overwrites its buffer. CO=192 layers split across 2 CO-half blocks
// (NT=6, acc=48 regs) so the 128-VGPR cap at 16 waves/CU cannot spill.
// STENCIL uses in-place accumulation (4 running sums) to stay under 128 VGPRs.
template<int CIN>
__global__ __launch_bounds__(512, 4)
void k_fused(const float* __restrict__ X, const float* __restrict__ pstats,
             const float* __restrict__ g, const float* __restrict__ bb,
             const __hip_bfloat16* __restrict__ Wt,
             float* __restrict__ Y, float* __restrict__ stats, int coTot) {
    constexpr int NCH = CIN / 16;
    constexpr int KdP = NCH * 96;
    __shared__ __align__(16) float Sb0[8192];    // 32 KB
    __shared__ __align__(16) float Sb1[8192];    // 32 KB
    __shared__ __align__(16) float risq[512];
    __shared__ float ls[192];
    int tid = threadIdx.x;
    // XCD-chunked bijective swizzle (nwg = 512 or 1024, both % 8 == 0)
    int nbx = gridDim.x;                         // 4 * (coTot/96)
    int nwg = nbx << 7;
    int flat = blockIdx.y * nbx + blockIdx.x;
    int wk = (flat & 7) * (nwg >> 3) + (flat >> 3);
    int b = wk / nbx;
    int rem = wk - b * nbx;
    int bx = rem & 3;
    int half = rem >> 2;
    int coOff = half * 96;
    int n0 = bx * 256 - 128;
    int jj = tid & 127;                          // quad index (stencil/stage)
    int sl = tid >> 7;                           // slot 0..3 (4 ch each)
    int sx = sl << 2;
    int lane = tid & 63, wv = tid >> 6;
    int col = lane & 15, quad = lane >> 4;
    const float invM = 1.0f / (float)M_TOT;

    {
        int gn = n0 + tid;
        int gi = gn >> 5, gj = gn & 31;
        int deg = (gi > 0) + (gi < 31) + (gj > 0) + (gj < 31);
        risq[tid] = rsqrtf((float)deg);
    }
    for (int t = tid; t < 192; t += 512) ls[t] = 0.f;

    // ---- quad-ownership constants ----
    int br = jj >> 4, bc = jj & 15;
    int ln00 = br * 64 + bc * 2;
    int gn00 = n0 + ln00;
    int gi0 = gn00 >> 5, gi1 = gi0 + 1;
    int gj0 = gn00 & 31, gj1 = gj0 + 1;
    bool gu = gi0 > 0, gd = gi1 < 31, gl = gj0 > 0, gr = gj1 < 31;
    int d00 = gu + (gi0 < 31) + gl + (gj0 < 31);
    int d01 = gu + (gi0 < 31) + (gj1 > 0) + gr;
    int d10 = (gi1 > 0) + gd + gl + (gj0 < 31);
    int d11 = (gi1 > 0) + gd + (gj1 > 0) + gr;
    float niv00 = -1.f / (float)d00, niv01 = -1.f / (float)d01;
    float niv10 = -1.f / (float)d10, niv11 = -1.f / (float)d11;
    float nm200 = 2.f * niv00, nm201 = 2.f * niv01, nm210 = 2.f * niv10, nm211 = 2.f * niv11;
    int upo = (br > 0) ? -32 : 0;
    int dno = (br < 7) ? 32 : 0;
    int a_u0 = SWA4(ln00 + upo),      a_u1 = SWA4(ln00 + 1 + upo);
    int a_d0 = SWA4(ln00 + 32 + dno), a_d1 = SWA4(ln00 + 33 + dno);
    int a_l0 = SWA4(ln00 - 1),        a_l1 = SWA4(ln00 + 31);
    int a_r0 = SWA4(ln00 + 2),        a_r1 = SWA4(ln00 + 34);
    int a_w00 = SWA4(ln00), a_w01 = SWA4(ln00 + 1);
    int a_w10 = SWA4(ln00 + 32), a_w11 = SWA4(ln00 + 33);

    // ---- A-fragment constants ----
    int an0 = 128 + wv * 32 + col, an1 = an0 + 16;
    int a_af0 = SWA4(an0), a_af1 = SWA4(an1);
    int sxA0 = ((quad & 1) * 2) << 2;            // slot pair within 16-ch group
    int sxA1 = sxA0 ^ 4;
    bool loHalf = (quad < 2);                    // K 0..15 vs 16..31 of K32 block
    float sd0, sd1;
    {
        int ga = n0 + an0, gb2 = n0 + an1;
        int dA = ((ga >> 5) > 0) + ((ga >> 5) < 31) + ((ga & 31) > 0) + ((ga & 31) < 31);
        int dB = ((gb2 >> 5) > 0) + ((gb2 >> 5) < 31) + ((gb2 & 31) > 0) + ((gb2 & 31) < 31);
        sd0 = sqrtf((float)dA); sd1 = sqrtf((float)dB);
    }

    f32x4 acc[2][6];
    #pragma unroll
    for (int t = 0; t < 2; ++t)
        #pragma unroll
        for (int n = 0; n < 6; ++n) acc[t][n] = Z4;

// In-place accumulation: 4 running sums, no named neighbor temporaries.
#define STENCIL(SA, SD, MODE)                                                   \
    {                                                                           \
        f32x4 o00 = LD4(SA, a_w00 ^ sx), o01 = LD4(SA, a_w01 ^ sx);             \
        f32x4 o10 = LD4(SA, a_w10 ^ sx), o11 = LD4(SA, a_w11 ^ sx);             \
        f32x4 s00 = o01 + o10;                                                  \
        f32x4 s11 = s00;                                                        \
        f32x4 s01 = o00 + o11;                                                  \
        f32x4 s10 = s01;                                                        \
        if (gu) { s00 += LD4(SA, a_u0 ^ sx); s01 += LD4(SA, a_u1 ^ sx); }       \
        if (gd) { s10 += LD4(SA, a_d0 ^ sx); s11 += LD4(SA, a_d1 ^ sx); }       \
        if (gl) { s00 += LD4(SA, a_l0 ^ sx); s10 += LD4(SA, a_l1 ^ sx); }       \
        if (gr) { s01 += LD4(SA, a_r0 ^ sx); s11 += LD4(SA, a_r1 ^ sx); }       \
        f32x4 v00, v01, v10, v11;                                               \
        if (MODE == 0) {                                                        \
            v00 = s00 * niv00; v01 = s01 * niv01;                               \
            v10 = s10 * niv10; v11 = s11 * niv11;                               \
        } else {                                                                \
            v00 = s00 * nm200 - LD4(SD, a_w00 ^ sx);                            \
            v01 = s01 * nm201 - LD4(SD, a_w01 ^ sx);                            \
            v10 = s10 * nm210 - LD4(SD, a_w10 ^ sx);                            \
            v11 = s11 * nm211 - LD4(SD, a_w11 ^ sx);                            \
        }                                                                       \
        ST4(SD, a_w00 ^ sx, v00); ST4(SD, a_w01 ^ sx, v01);                     \
        ST4(SD, a_w10 ^ sx, v10); ST4(SD, a_w11 ^ sx, v11);                     \
    }

    auto readA = [&](const float* buf, bf16x8& A0, bf16x8& A1) {
        f32x4 lo0 = LD4(buf, a_af0 ^ sxA0), hi0 = LD4(buf, a_af0 ^ sxA1);
        f32x4 lo1 = LD4(buf, a_af1 ^ sxA0), hi1 = LD4(buf, a_af1 ^ sxA1);
        A0 = pack8(lo0 * sd0, hi0 * sd0);
        A1 = pack8(lo1 * sd1, hi1 * sd1);
    };
    auto MMADO = [&](int cs, int j, bf16x8 a0, bf16x8 a1) {
        const __hip_bfloat16* Bp = Wt + (size_t)(coOff + col) * KdP + cs * 96 + j * 32 + quad * 8;
        #pragma unroll
        for (int n = 0; n < 6; ++n) {
            bf16x8 bf = *(const bf16x8*)(Bp + (size_t)(n * 16) * KdP);
            acc[0][n] = __builtin_amdgcn_mfma_f32_16x16x32_bf16(a0, bf, acc[0][n], 0, 0, 0);
            acc[1][n] = __builtin_amdgcn_mfma_f32_16x16x32_bf16(a1, bf, acc[1][n], 0, 0, 0);
        }
    };
    auto STAGE = [&](float* SD, int cs) {
        int gn0 = n0 + 4 * jj;
        bool inb = (gn0 >= 0) && (gn0 < 1024);
        f32x4 r4 = *(const f32x4*)(risq + 4 * jj);
        f32x4 vv[4];
        #pragma unroll
        for (int e = 0; e < 4; ++e) {
            int cglob = cs * 16 + sl * 4 + e;
            float mn = pstats[cglob] * invM;
            float vr = pstats[CIN + cglob] * invM - mn * mn;
            float scv = rsqrtf(vr + 1e-5f) * g[cglob];
            float ofv = bb[cglob] - mn * scv;
            f32x4 v = Z4;
            if (inb) v = *(const f32x4*)(X + (((size_t)b * CIN + cglob) << 10) + gn0);
            #pragma unroll
            for (int q2 = 0; q2 < 4; ++q2) {
                float xx = v[q2] * scv + ofv;
                xx = xx > 0.f ? xx : 0.f;
                v[q2] = xx * r4[q2];
            }
            vv[e] = v;
        }
        #pragma unroll
        for (int i2 = 0; i2 < 4; ++i2) {
            int ln = 4 * jj + i2;
            f32x4 w0 = (f32x4){vv[0][i2], vv[1][i2], vv[2][i2], vv[3][i2]};
            ST4(SD, SWA4(ln) ^ sx, w0);
        }
    };

    bf16x8 zf = pack8(Z4, Z4);
    float* P = Sb0;
    float* Q = Sb1;
    __syncthreads();                 // risq/ls ready
    STAGE(P, 0);
    __syncthreads();
    for (int cs = 0; cs < NCH; ++cs) {
        bf16x8 pa0, pa1, ca0, ca1, af0, af1;
        STENCIL(P, Q, 0);            // S1 -> Q
        readA(P, pa0, pa1);          // hold S0 (P overwritten next phase)
        __syncthreads();
        STENCIL(Q, P, 1);            // S2 -> P (old = S0 own-slot)
        readA(Q, ca0, ca1);          // S1
        af0 = loHalf ? pa0 : ca0; af1 = loHalf ? pa1 : ca1;
        MMADO(cs, 0, af0, af1);      // K-block (S0|S1)
        __syncthreads();
        STENCIL(P, Q, 1);            // S3 -> Q (old = S1)
        readA(P, pa0, pa1);          // hold S2
        __syncthreads();
        STENCIL(Q, P, 1);            // S4 -> P (old = S2)
        readA(Q, ca0, ca1);          // S3
        af0 = loHalf ? pa0 : ca0; af1 = loHalf ? pa1 : ca1;
        MMADO(cs, 1, af0, af1);      // K-block (S2|S3)
        __syncthreads();
        readA(P, ca0, ca1);          // S4
        af0 = loHalf ? ca0 : zf; af1 = loHalf ? ca1 : zf;
        MMADO(cs, 2, af0, af1);      // K-block (S4|0)
        if (cs + 1 < NCH) STAGE(Q, cs + 1);
        __syncthreads();
        float* t = P; P = Q; Q = t;
    }

    // ---- epilogue: Y store + per-channel stats (this CO-half) ----
    int gnb = bx * 256;
    float* sb = stats + coOff;
    #pragma unroll
    for (int t = 0; t < 2; ++t) {
        int gn0 = gnb + ((2 * wv + t) << 4) + quad * 4;
        #pragma unroll
        for (int n = 0; n < 6; ++n) {
            int lcg = n * 16 + col;
            f32x4 val = acc[t][n];
            *(f32x4*)(Y + (((size_t)b * coTot + coOff + lcg) << 10) + gn0) = val;
            float s1 = val[0] + val[1] + val[2] + val[3];
            float s2 = val[0]*val[0] + val[1]*val[1] + val[2]*val[2] + val[3]*val[3];
            s1 += __shfl_xor(s1, 16, 64); s1 += __shfl_xor(s1, 32, 64);
            s2 += __shfl_xor(s2, 16, 64); s2 += __shfl_xor(s2, 32, 64);
            if (quad == 0) { atomicAdd(&ls[lcg], s1); atomicAdd(&ls[96 + lcg], s2); }
        }
    }
    __syncthreads();
    for (int t = tid; t < 96; t += 512) {
        atomicAdd(&sb[t], ls[t]);
        atomicAdd(&sb[coTot + t], ls[96 + t]);
    }
}

// ---------------------------------------------------------------------------
// Classifier (multi-block r3 form: one block per (b, o); fused BN6+ReLU).
__global__ __launch_bounds__(256)
void k_classifier(const float* __restrict__ h, const float* __restrict__ stats,
                  const float* __restrict__ g, const float* __restrict__ bb,
                  const float* __restrict__ w, const float* __restrict__ bias,
                  float* __restrict__ out) {
    int b = blockIdx.x, o = blockIdx.y;
    const float4* hb = (const float4*)(h + (size_t)b * 96 * GV);
    const float4* wo = (const float4*)(w + (size_t)o * 96 * GV);
    const float invM = 1.0f / (float)M_TOT;
    float acc = 0.f;
    for (int f = threadIdx.x; f < 96 * GV / 4; f += 256) {
        int c = f >> 8;
        float mn = stats[c] * invM;
        float vr = stats[96 + c] * invM - mn * mn;
        float sc = rsqrtf(vr + 1e-5f) * g[c];
        float of = bb[c] - mn * sc;
        float4 a = hb[f], c4 = wo[f];
        float x0 = fmaxf(a.x * sc + of, 0.f);
        float x1 = fmaxf(a.y * sc + of, 0.f);
        float x2 = fmaxf(a.z * sc + of, 0.f);
        float x3 = fmaxf(a.w * sc + of, 0.f);
        acc += x0 * c4.x + x1 * c4.y + x2 * c4.z + x3 * c4.w;
    }
    #pragma unroll
    for (int off = 32; off > 0; off >>= 1) acc += __shfl_down(acc, off, 64);
    __shared__ float red[4];
    int lane = threadIdx.x & 63, wvv = threadIdx.x >> 6;
    if (lane == 0) red[wvv] = acc;
    __syncthreads();
    if (threadIdx.x == 0) out[b * 10 + o] = red[0] + red[1] + red[2] + red[3] + bias[o];
}

// ---------------------------------------------------------------------------
extern "C" void kernel_launch(void* const* d_in, const int* in_sizes, int n_in,
                              void* d_out, int out_size, void* d_ws, size_t ws_size,
                              hipStream_t stream) {
    const float* x = (const float*)d_in[0];
    const float* wts[7]; const float* gs[7]; const float* bs[7];
    for (int i = 0; i < 7; ++i) {
        wts[i] = (const float*)d_in[2 + 3 * i];
        gs[i]  = (const float*)d_in[3 + 3 * i];
        bs[i]  = (const float*)d_in[4 + 3 * i];
    }
    const float* clfw = (const float*)d_in[23];
    const float* clfb = (const float*)d_in[24];
    float* out = (float*)d_out;

    const size_t BIG = (size_t)M_TOT * 192;
    float* ws = (float*)d_ws;
    float* bufA = ws;
    float* bufB = ws + BIG;
    float* stats = ws + 2 * BIG;
    __hip_bfloat16* Wb = (__hip_bfloat16*)(stats + 7 * 384);
    __hip_bfloat16* F0 = Wb + WTOT;

    hipMemsetAsync(stats, 0, 7 * 384 * sizeof(float), stream);
    hipLaunchKernelGGL(k_convw_all, dim3(864, 7), dim3(256), 0, stream,
                       wts[0], wts[1], wts[2], wts[3], wts[4], wts[5], wts[6], Wb);

    hipLaunchKernelGGL(k_cheb0, dim3(BATCH), dim3(512), 0, stream, x, F0);
    hipLaunchKernelGGL(k_gemm_l0, dim3(M_TOT / 128), dim3(256), 0, stream,
                       F0, Wb + WOFF0, bufA, stats);

    // CHANNELS: l1 (96,96) l2 (96,96) l3 (96,192) l4 (192,192) l5 (192,192) l6 (192,96)
    hipLaunchKernelGGL((k_fused<96>),  dim3(4, BATCH), dim3(512), 0, stream,
                       bufA, stats + 0 * 384, gs[0], bs[0], Wb + WOFF1, bufB, stats + 1 * 384, 96);
    hipLaunchKernelGGL((k_fused<96>),  dim3(4, BATCH), dim3(512), 0, stream,
                       bufB, stats + 1 * 384, gs[1], bs[1], Wb + WOFF2, bufA, stats + 2 * 384, 96);
    hipLaunchKernelGGL((k_fused<96>),  dim3(8, BATCH), dim3(512), 0, stream,
                       bufA, stats + 2 * 384, gs[2], bs[2], Wb + WOFF3, bufB, stats + 3 * 384, 192);
    hipLaunchKernelGGL((k_fused<192>), dim3(8, BATCH), dim3(512), 0, stream,
                       bufB, stats + 3 * 384, gs[3], bs[3], Wb + WOFF4, bufA, stats + 4 * 384, 192);
    hipLaunchKernelGGL((k_fused<192>), dim3(8, BATCH), dim3(512), 0, stream,
                       bufA, stats + 4 * 384, gs[4], bs[4], Wb + WOFF5, bufB, stats + 5 * 384, 192);
    hipLaunchKernelGGL((k_fused<192>), dim3(4, BATCH), dim3(512), 0, stream,
                       bufB, stats + 5 * 384, gs[5], bs[5], Wb + WOFF6, bufA, stats + 6 * 384, 96);

    hipLaunchKernelGGL(k_classifier, dim3(BATCH, 10), dim3(256), 0, stream,
                       bufA, stats + 6 * 384, gs[6], bs[6], clfw, clfb, out);
}

// Round 11
// 1023.836 us; speedup vs baseline: 2.9009x; 2.9009x over previous
//
#include <hip/hip_runtime.h>
#include <hip/hip_bf16.h>

#define GV 1024
#define BATCH 128
#define M_TOT (BATCH * GV)   // 131072 rows
#define CHEB_K 5

typedef __bf16 bf16x8 __attribute__((ext_vector_type(8)));
typedef float  f32x4  __attribute__((ext_vector_type(4)));

// Wb offsets (bf16 elems). L0: [96][32] (f=k*3+c, pad to 32).
// L1..6 PHASE-MAJOR: [ch][d][Co][32] — element (ch,d,c,cl) = W[c][(ch*32+cl)*5+d].
// Each (ch,d) slab = Co*32 contiguous bf16 (12KB @ Co=192) -> coalesced WLOAD.
#define WOFF0 0
#define WOFF1 3072
#define WOFF2 49152
#define WOFF3 95232
#define WOFF4 187392
#define WOFF5 371712
#define WOFF6 556032
#define WTOT  648192

// 8-slot swizzle: float addr of (node ln, slot s) = SWA(ln) ^ (s*4)
#define SWA(ln) ((ln) * 32 + ((((ln) + ((ln) >> 3)) & 7) * 4))
#define LD4(B, A) (*(const f32x4*)((B) + (A)))
#define ST4(B, A, V) (*(f32x4*)((B) + (A)) = (V))
#define Z4 ((f32x4){0.f, 0.f, 0.f, 0.f})

// ---------------------------------------------------------------------------
__global__ void k_convw_all(const float* __restrict__ w0, const float* __restrict__ w1,
                            const float* __restrict__ w2, const float* __restrict__ w3,
                            const float* __restrict__ w4, const float* __restrict__ w5,
                            const float* __restrict__ w6, __hip_bfloat16* __restrict__ Wb) {
    const int li = blockIdx.y;
    const int CI[7]     = {3, 96, 96, 96, 192, 192, 192};
    const int COt[7]    = {96, 96, 96, 192, 192, 192, 96};
    const int SZ[7]     = {3072, 46080, 46080, 92160, 184320, 184320, 92160};
    const size_t OFF[7] = {WOFF0, WOFF1, WOFF2, WOFF3, WOFF4, WOFF5, WOFF6};
    const float* Ws[7]  = {w0, w1, w2, w3, w4, w5, w6};
    int idx = blockIdx.x * 256 + threadIdx.x;
    if (idx >= SZ[li]) return;
    const float* W = Ws[li];
    float v = 0.f;
    if (li == 0) {
        int f = idx & 31;
        if (f < 15) { int o = idx >> 5; int k = f / 3, c = f % 3; v = W[o * 15 + c * 5 + k]; }
    } else {
        int Ci = CI[li], Co = COt[li];
        int cl = idx & 31;
        int rest = idx >> 5;
        int c = rest % Co;
        int q = rest / Co;
        int d = q % 5, ch = q / 5;
        v = W[(size_t)c * 5 * Ci + (ch * 32 + cl) * 5 + d];
    }
    Wb[OFF[li] + idx] = __float2bfloat16(v);
}

// ---------------------------------------------------------------------------
__global__ __launch_bounds__(512, 4)
void k_cheb0(const float* __restrict__ X, __hip_bfloat16* __restrict__ F) {
    __shared__ float T[3][3072];
    int tid = threadIdx.x;
    int b = blockIdx.x;
    size_t fBase = ((size_t)b) << 10;
    for (int i = tid; i < 3072; i += 512) {
        int u = i / 3, c = i - (i / 3) * 3;
        float v = X[((size_t)b * 3 + c) * GV + u];
        F[(fBase + u) * 32 + c] = __float2bfloat16(v);
        int gi = u >> 5, gj = u & 31;
        int deg = (gi > 0) + (gi < 31) + (gj > 0) + (gj < 31);
        T[0][i] = v * rsqrtf((float)deg);
    }
    for (int i = tid; i < 1024 * 17; i += 512) {
        int u = i / 17, f = i - (i / 17) * 17;
        F[(fBase + u) * 32 + 15 + f] = __float2bfloat16(0.f);
    }
    __syncthreads();
    for (int k = 1; k < CHEB_K; ++k) {
        const float* src = T[(k - 1) % 3];
        const float* old = T[(k + 1) % 3];
        float* dst = T[k % 3];
        for (int i = tid; i < 3072; i += 512) {
            int u = i / 3, c = i - (i / 3) * 3;
            int gi = u >> 5, gj = u & 31;
            float s = 0.f;
            if (gi > 0)  s += src[i - 96];
            if (gi < 31) s += src[i + 96];
            if (gj > 0)  s += src[i - 3];
            if (gj < 31) s += src[i + 3];
            int deg = (gi > 0) + (gi < 31) + (gj > 0) + (gj < 31);
            float invdeg = (deg == 4) ? 0.25f : (deg == 3 ? (1.f / 3.f) : 0.5f);
            float val = (k == 1) ? (-s * invdeg) : (-2.f * invdeg * s - old[i]);
            dst[i] = val;
            F[(fBase + u) * 32 + k * 3 + c] = __float2bfloat16(val * sqrtf((float)deg));
        }
        __syncthreads();
    }
}

// ---------------------------------------------------------------------------
__global__ __launch_bounds__(256, 2)
void k_gemm_l0(const __hip_bfloat16* __restrict__ A, const __hip_bfloat16* __restrict__ Bw,
               float* __restrict__ Y, float* __restrict__ stats) {
    __shared__ float ls[192];
    int tid = threadIdx.x;
    for (int t = tid; t < 192; t += 256) ls[t] = 0.f;
    __syncthreads();
    int lane = tid & 63, wv = tid >> 6;
    int col = lane & 15, quad = lane >> 4;
    size_t m0 = (size_t)blockIdx.x * 128 + wv * 32;
    f32x4 acc[2][6];
    #pragma unroll
    for (int t = 0; t < 2; ++t)
        #pragma unroll
        for (int n = 0; n < 6; ++n) acc[t][n] = Z4;
    bf16x8 a0 = *(const bf16x8*)(A + (m0 + col) * 32 + quad * 8);
    bf16x8 a1 = *(const bf16x8*)(A + (m0 + 16 + col) * 32 + quad * 8);
    #pragma unroll
    for (int n = 0; n < 6; ++n) {
        bf16x8 bf = *(const bf16x8*)(Bw + (size_t)(n * 16 + col) * 32 + quad * 8);
        acc[0][n] = __builtin_amdgcn_mfma_f32_16x16x32_bf16(a0, bf, acc[0][n], 0, 0, 0);
        acc[1][n] = __builtin_amdgcn_mfma_f32_16x16x32_bf16(a1, bf, acc[1][n], 0, 0, 0);
    }
    int b = (int)(m0 >> 10);
    int v0 = (int)(m0 & 1023);
    #pragma unroll
    for (int t = 0; t < 2; ++t) {
        #pragma unroll
        for (int n = 0; n < 6; ++n) {
            int cg = n * 16 + col;
            int vv = v0 + t * 16 + quad * 4;
            f32x4 val = acc[t][n];
            *(f32x4*)(Y + ((size_t)b * 96 + cg) * 1024 + vv) = val;
            float s1 = val[0] + val[1] + val[2] + val[3];
            float s2 = val[0]*val[0] + val[1]*val[1] + val[2]*val[2] + val[3]*val[3];
            s1 += __shfl_xor(s1, 16, 64); s1 += __shfl_xor(s1, 32, 64);
            s2 += __shfl_xor(s2, 16, 64); s2 += __shfl_xor(s2, 32, 64);
            if (quad == 0) { atomicAdd(&ls[cg], s1); atomicAdd(&ls[96 + cg], s2); }
        }
    }
    __syncthreads();
    for (int t = tid; t < 192; t += 256) atomicAdd(&stats[t], ls[t]);
}

// ---------------------------------------------------------------------------
__device__ __forceinline__ bf16x8 pack8(f32x4 lo, f32x4 hi) {
    union { __hip_bfloat16 h[8]; bf16x8 v; } u;
    #pragma unroll
    for (int e = 0; e < 4; ++e) { u.h[e] = __float2bfloat16(lo[e]); u.h[4 + e] = __float2bfloat16(hi[e]); }
    return u.v;
}

// ---------------------------------------------------------------------------
// FUSED layer (r8 base: 32-ch chunks, all-LDS stencil, 1 block/CU, parity flip)
// + W double-buffered in LDS: phase (ch,d)'s 2*CO KB slab is prefetched
// cooperatively (coalesced, phase-major layout) during phase (ch,d-1) and MFMA
// reads B-fragments from LDS — replaces per-wave uncoalesced 1920B-stride
// global loads (64 L2 transactions per wave-load, reissued every phase).
template<int CIN, int NT>
__global__ __launch_bounds__(512, 2)
void k_fused(const float* __restrict__ X, const float* __restrict__ pstats,
             const float* __restrict__ g, const float* __restrict__ bb,
             const __hip_bfloat16* __restrict__ Wt,
             float* __restrict__ Y, float* __restrict__ stats) {
    constexpr int CO = NT * 16;
    constexpr int NCH = CIN / 32;
    __shared__ __align__(16) float Sb0[16384];          // 64 KB
    __shared__ __align__(16) float Sb1[16384];          // 64 KB
    __shared__ __align__(16) __hip_bfloat16 wls[2][CO * 32];  // 2x (12 or 6) KB
    __shared__ __align__(16) float risq[512];
    __shared__ float ls[2 * CO];
    int tid = threadIdx.x;
    // XCD-chunked bijective swizzle (nwg = 512 = 8*64)
    int flat = (blockIdx.y << 2) | blockIdx.x;
    int wk = ((flat & 7) << 6) | (flat >> 3);
    int bx = wk & 3;
    int b  = wk >> 2;
    int n0 = bx * 256 - 128;
    int jj = tid & 127, kg = tid >> 7;
    int lane = tid & 63, wv = tid >> 6;
    int col = lane & 15, quad = lane >> 4;
    const float invM = 1.0f / (float)M_TOT;

    {
        int gn = n0 + tid;
        int gi = gn >> 5, gj = gn & 31;
        int deg = (gi > 0) + (gi < 31) + (gj > 0) + (gj < 31);
        risq[tid] = rsqrtf((float)deg);
    }
    for (int t = tid; t < 2 * CO; t += 512) ls[t] = 0.f;

    // ---- quad-ownership constants ----
    int br = jj >> 4, bc = jj & 15;
    int ln00 = br * 64 + bc * 2;
    int gn00 = n0 + ln00;
    int gi0 = gn00 >> 5, gi1 = gi0 + 1;
    int gj0 = gn00 & 31, gj1 = gj0 + 1;
    bool gu = gi0 > 0, gd = gi1 < 31, gl = gj0 > 0, gr = gj1 < 31;
    int d00 = gu + (gi0 < 31) + gl + (gj0 < 31);
    int d01 = gu + (gi0 < 31) + (gj1 > 0) + gr;
    int d10 = (gi1 > 0) + gd + gl + (gj0 < 31);
    int d11 = (gi1 > 0) + gd + (gj1 > 0) + gr;
    float niv00 = -1.f / (float)d00, niv01 = -1.f / (float)d01;
    float niv10 = -1.f / (float)d10, niv11 = -1.f / (float)d11;
    float nm200 = 2.f * niv00, nm201 = 2.f * niv01, nm210 = 2.f * niv10, nm211 = 2.f * niv11;
    int upo = (br > 0) ? -32 : 0;
    int dno = (br < 7) ? 32 : 0;
    int a_u0 = SWA(ln00 + upo),      a_u1 = SWA(ln00 + 1 + upo);
    int a_d0 = SWA(ln00 + 32 + dno), a_d1 = SWA(ln00 + 33 + dno);
    int a_l0 = SWA(ln00 - 1),        a_l1 = SWA(ln00 + 31);
    int a_r0 = SWA(ln00 + 2),        a_r1 = SWA(ln00 + 34);
    int a_w00 = SWA(ln00), a_w01 = SWA(ln00 + 1);
    int a_w10 = SWA(ln00 + 32), a_w11 = SWA(ln00 + 33);
    int cgx0 = (2 * kg) * 4, cgx1 = (2 * kg + 1) * 4;

    // ---- A-fragment constants ----
    int an0 = 128 + wv * 32 + col, an1 = an0 + 16;
    int a_af0 = SWA(an0), a_af1 = SWA(an1);
    int g0x = (2 * quad) * 4, g1x = (2 * quad + 1) * 4;
    float sd0, sd1;
    {
        int ga = n0 + an0, gb2 = n0 + an1;
        int dA = ((ga >> 5) > 0) + ((ga >> 5) < 31) + ((ga & 31) > 0) + ((ga & 31) < 31);
        int dB = ((gb2 >> 5) > 0) + ((gb2 >> 5) < 31) + ((gb2 & 31) > 0) + ((gb2 & 31) < 31);
        sd0 = sqrtf((float)dA); sd1 = sqrtf((float)dB);
    }

    f32x4 acc[2][NT];
    #pragma unroll
    for (int t = 0; t < 2; ++t)
        #pragma unroll
        for (int n = 0; n < NT; ++n) acc[t][n] = Z4;

// All-LDS stencil, running-sum form (minimal live temporaries).
#define STENCIL(SA, SD, MODE)                                                   \
    {                                                                           \
        _Pragma("unroll")                                                       \
        for (int cgi = 0; cgi < 2; ++cgi) {                                     \
            int cgx = cgi ? cgx1 : cgx0;                                        \
            f32x4 o00 = LD4(SA, a_w00 ^ cgx), o01 = LD4(SA, a_w01 ^ cgx);       \
            f32x4 o10 = LD4(SA, a_w10 ^ cgx), o11 = LD4(SA, a_w11 ^ cgx);       \
            f32x4 s00 = o01 + o10;                                              \
            f32x4 s11 = s00;                                                    \
            f32x4 s01 = o00 + o11;                                              \
            f32x4 s10 = s01;                                                    \
            if (gu) { s00 += LD4(SA, a_u0 ^ cgx); s01 += LD4(SA, a_u1 ^ cgx); } \
            if (gd) { s10 += LD4(SA, a_d0 ^ cgx); s11 += LD4(SA, a_d1 ^ cgx); } \
            if (gl) { s00 += LD4(SA, a_l0 ^ cgx); s10 += LD4(SA, a_l1 ^ cgx); } \
            if (gr) { s01 += LD4(SA, a_r0 ^ cgx); s11 += LD4(SA, a_r1 ^ cgx); } \
            f32x4 v00, v01, v10, v11;                                           \
            if (MODE == 0) {                                                    \
                v00 = s00 * niv00; v01 = s01 * niv01;                           \
                v10 = s10 * niv10; v11 = s11 * niv11;                           \
            } else {                                                            \
                v00 = s00 * nm200 - LD4(SD, a_w00 ^ cgx);                       \
                v01 = s01 * nm201 - LD4(SD, a_w01 ^ cgx);                       \
                v10 = s10 * nm210 - LD4(SD, a_w10 ^ cgx);                       \
                v11 = s11 * nm211 - LD4(SD, a_w11 ^ cgx);                       \
            }                                                                   \
            ST4(SD, a_w00 ^ cgx, v00); ST4(SD, a_w01 ^ cgx, v01);               \
            ST4(SD, a_w10 ^ cgx, v10); ST4(SD, a_w11 ^ cgx, v11);               \
        }                                                                       \
    }

    // cooperative coalesced prefetch of phase slab (ch,d) -> LDS wd
    auto WLOAD = [&](__hip_bfloat16* wd, int cs, int d) {
        const __hip_bfloat16* src = Wt + ((size_t)(cs * 5 + d) * CO) * 32;
        #pragma unroll
        for (int t = tid; t < CO * 4; t += 512)
            *(bf16x8*)(wd + t * 8) = *(const bf16x8*)(src + t * 8);
    };
    auto MMA = [&](const float* SA, const __hip_bfloat16* wl) {
        f32x4 lo0 = LD4(SA, a_af0 ^ g0x), hi0 = LD4(SA, a_af0 ^ g1x);
        f32x4 lo1 = LD4(SA, a_af1 ^ g0x), hi1 = LD4(SA, a_af1 ^ g1x);
        bf16x8 af0 = pack8(lo0 * sd0, hi0 * sd0);
        bf16x8 af1 = pack8(lo1 * sd1, hi1 * sd1);
        #pragma unroll
        for (int n = 0; n < NT; ++n) {
            bf16x8 bf = *(const bf16x8*)(wl + (n * 16 + col) * 32 + quad * 8);
            acc[0][n] = __builtin_amdgcn_mfma_f32_16x16x32_bf16(af0, bf, acc[0][n], 0, 0, 0);
            acc[1][n] = __builtin_amdgcn_mfma_f32_16x16x32_bf16(af1, bf, acc[1][n], 0, 0, 0);
        }
    };
    auto STAGE = [&](float* SD, int cs) {
        const float* Xc = X + ((size_t)b * CIN + cs * 32) * 1024;
        int gn0 = n0 + 4 * jj;
        bool inb = (gn0 >= 0) && (gn0 < 1024);
        f32x4 r4 = *(const f32x4*)(risq + 4 * jj);
        #pragma unroll
        for (int grp = 0; grp < 2; ++grp) {
            f32x4 vv[4];
            #pragma unroll
            for (int e = 0; e < 4; ++e) {
                int cglob = cs * 32 + 8 * kg + grp * 4 + e;
                float mn = pstats[cglob] * invM;
                float vr = pstats[CIN + cglob] * invM - mn * mn;
                float sc = rsqrtf(vr + 1e-5f) * g[cglob];
                float of = bb[cglob] - mn * sc;
                f32x4 v = Z4;
                if (inb) v = *(const f32x4*)(Xc + (size_t)(8 * kg + grp * 4 + e) * 1024 + gn0);
                #pragma unroll
                for (int q2 = 0; q2 < 4; ++q2) {
                    float xx = v[q2] * sc + of;
                    xx = xx > 0.f ? xx : 0.f;
                    v[q2] = xx * r4[q2];
                }
                vv[e] = v;
            }
            int cgx = grp ? cgx1 : cgx0;
            #pragma unroll
            for (int i2 = 0; i2 < 4; ++i2) {
                int ln = 4 * jj + i2;
                f32x4 w0 = (f32x4){vv[0][i2], vv[1][i2], vv[2][i2], vv[3][i2]};
                ST4(SD, SWA(ln) ^ cgx, w0);
            }
        }
    };

    float* P = Sb0;
    float* Q = Sb1;
    __hip_bfloat16* wA = wls[0];
    __hip_bfloat16* wB = wls[1];
    __syncthreads();                       // risq/ls ready (race fix)
    WLOAD(wA, 0, 0);
    STAGE(P, 0);
    __syncthreads();
    for (int ch = 0; ch < NCH; ++ch) {
        STENCIL(P, Q, 0);  WLOAD(wB, ch, 1);  MMA(P, wA);  __syncthreads();
        STENCIL(Q, P, 1);  WLOAD(wA, ch, 2);  MMA(Q, wB);  __syncthreads();
        STENCIL(P, Q, 1);  WLOAD(wB, ch, 3);  MMA(P, wA);  __syncthreads();
        STENCIL(Q, P, 1);  WLOAD(wA, ch, 4);  MMA(Q, wB);  __syncthreads();
        if (ch + 1 < NCH) { WLOAD(wB, ch + 1, 0); STAGE(Q, ch + 1); }
        MMA(P, wA);
        __syncthreads();
        float* t = P; P = Q; Q = t;
        __hip_bfloat16* tw = wA; wA = wB; wB = tw;
    }

    // ---- epilogue: Y store (16B) + per-channel stats ----
    int gnb = bx * 256;
    #pragma unroll
    for (int t = 0; t < 2; ++t) {
        int gn0 = gnb + ((2 * wv + t) << 4) + quad * 4;
        #pragma unroll
        for (int n = 0; n < NT; ++n) {
            int cg = n * 16 + col;
            f32x4 val = acc[t][n];
            *(f32x4*)(Y + ((size_t)b * CO + cg) * 1024 + gn0) = val;
            float s1 = val[0] + val[1] + val[2] + val[3];
            float s2 = val[0]*val[0] + val[1]*val[1] + val[2]*val[2] + val[3]*val[3];
            s1 += __shfl_xor(s1, 16, 64); s1 += __shfl_xor(s1, 32, 64);
            s2 += __shfl_xor(s2, 16, 64); s2 += __shfl_xor(s2, 32, 64);
            if (quad == 0) { atomicAdd(&ls[cg], s1); atomicAdd(&ls[CO + cg], s2); }
        }
    }
    __syncthreads();
    for (int t = tid; t < 2 * CO; t += 512) atomicAdd(&stats[t], ls[t]);
}

// ---------------------------------------------------------------------------
// Classifier split-K: grid (B, 8); each block does 12 channels x 1024 nodes
// for all 10 outputs, fused BN6+ReLU; partials atomicAdd'ed into clsacc.
__global__ __launch_bounds__(256)
void k_cls_part(const float* __restrict__ h, const float* __restrict__ stats,
                const float* __restrict__ g, const float* __restrict__ bb,
                const float* __restrict__ w, float* __restrict__ clsacc) {
    int b = blockIdx.x, s = blockIdx.y, tid = threadIdx.x;
    const float4* hb = (const float4*)(h + (size_t)b * 96 * GV);
    const float4* w4 = (const float4*)w;
    const float invM = 1.0f / (float)M_TOT;
    float acc[10];
    #pragma unroll
    for (int o = 0; o < 10; ++o) acc[o] = 0.f;
    for (int it = 0; it < 12; ++it) {
        int c = s * 12 + it;
        int f = c * 256 + tid;           // float4 index into [96][256]
        float mn = stats[c] * invM;
        float vr = stats[96 + c] * invM - mn * mn;
        float sc = rsqrtf(vr + 1e-5f) * g[c];
        float of = bb[c] - mn * sc;
        float4 a = hb[f];
        float x0 = fmaxf(a.x * sc + of, 0.f);
        float x1 = fmaxf(a.y * sc + of, 0.f);
        float x2 = fmaxf(a.z * sc + of, 0.f);
        float x3 = fmaxf(a.w * sc + of, 0.f);
        #pragma unroll
        for (int o = 0; o < 10; ++o) {
            float4 c4 = w4[(size_t)o * 24576 + f];
            acc[o] += x0 * c4.x + x1 * c4.y + x2 * c4.z + x3 * c4.w;
        }
    }
    __shared__ float red[4][10];
    int lane = tid & 63, wvv = tid >> 6;
    #pragma unroll
    for (int o = 0; o < 10; ++o) {
        float v = acc[o];
        #pragma unroll
        for (int off = 32; off > 0; off >>= 1) v += __shfl_down(v, off, 64);
        if (lane == 0) red[wvv][o] = v;
    }
    __syncthreads();
    if (tid < 10) atomicAdd(&clsacc[b * 10 + tid],
                            red[0][tid] + red[1][tid] + red[2][tid] + red[3][tid]);
}

__global__ void k_cls_fin(const float* __restrict__ clsacc, const float* __restrict__ bias,
                          float* __restrict__ out) {
    int i = blockIdx.x * 256 + threadIdx.x;
    if (i < BATCH * 10) out[i] = clsacc[i] + bias[i % 10];
}

// ---------------------------------------------------------------------------
extern "C" void kernel_launch(void* const* d_in, const int* in_sizes, int n_in,
                              void* d_out, int out_size, void* d_ws, size_t ws_size,
                              hipStream_t stream) {
    const float* x = (const float*)d_in[0];
    const float* wts[7]; const float* gs[7]; const float* bs[7];
    for (int i = 0; i < 7; ++i) {
        wts[i] = (const float*)d_in[2 + 3 * i];
        gs[i]  = (const float*)d_in[3 + 3 * i];
        bs[i]  = (const float*)d_in[4 + 3 * i];
    }
    const float* clfw = (const float*)d_in[23];
    const float* clfb = (const float*)d_in[24];
    float* out = (float*)d_out;

    const size_t BIG = (size_t)M_TOT * 192;
    float* ws = (float*)d_ws;
    float* bufA = ws;
    float* bufB = ws + BIG;
    float* stats = ws + 2 * BIG;                  // 7*384 floats
    float* clsacc = stats + 7 * 384;              // 1280 floats
    __hip_bfloat16* Wb = (__hip_bfloat16*)(clsacc + 1280);
    __hip_bfloat16* F0 = Wb + WTOT;

    hipMemsetAsync(stats, 0, (7 * 384 + 1280) * sizeof(float), stream);
    hipLaunchKernelGGL(k_convw_all, dim3(720, 7), dim3(256), 0, stream,
                       wts[0], wts[1], wts[2], wts[3], wts[4], wts[5], wts[6], Wb);

    hipLaunchKernelGGL(k_cheb0, dim3(BATCH), dim3(512), 0, stream, x, F0);
    hipLaunchKernelGGL(k_gemm_l0, dim3(M_TOT / 128), dim3(256), 0, stream,
                       F0, Wb + WOFF0, bufA, stats);

    // CHANNELS: l1 (96,96) l2 (96,96) l3 (96,192) l4 (192,192) l5 (192,192) l6 (192,96)
    dim3 fg(4, BATCH);
    hipLaunchKernelGGL((k_fused<96, 6>),   fg, dim3(512), 0, stream,
                       bufA, stats + 0 * 384, gs[0], bs[0], Wb + WOFF1, bufB, stats + 1 * 384);
    hipLaunchKernelGGL((k_fused<96, 6>),   fg, dim3(512), 0, stream,
                       bufB, stats + 1 * 384, gs[1], bs[1], Wb + WOFF2, bufA, stats + 2 * 384);
    hipLaunchKernelGGL((k_fused<96, 12>),  fg, dim3(512), 0, stream,
                       bufA, stats + 2 * 384, gs[2], bs[2], Wb + WOFF3, bufB, stats + 3 * 384);
    hipLaunchKernelGGL((k_fused<192, 12>), fg, dim3(512), 0, stream,
                       bufB, stats + 3 * 384, gs[3], bs[3], Wb + WOFF4, bufA, stats + 4 * 384);
    hipLaunchKernelGGL((k_fused<192, 12>), fg, dim3(512), 0, stream,
                       bufA, stats + 4 * 384, gs[4], bs[4], Wb + WOFF5, bufB, stats + 5 * 384);
    hipLaunchKernelGGL((k_fused<192, 6>),  fg, dim3(512), 0, stream,
                       bufB, stats + 5 * 384, gs[5], bs[5], Wb + WOFF6, bufA, stats + 6 * 384);

    hipLaunchKernelGGL(k_cls_part, dim3(BATCH, 8), dim3(256), 0, stream,
                       bufA, stats + 6 * 384, gs[6], bs[6], clfw, clsacc);
    hipLaunchKernelGGL(k_cls_fin, dim3((BATCH * 10 + 255) / 256), dim3(256), 0, stream,
                       clsacc, clfb, out);
}